// Round 5
// baseline (1121.940 us; speedup 1.0000x reference)
//
#include <hip/hip_runtime.h>
#include <hip/hip_cooperative_groups.h>

namespace cg = cooperative_groups;

// EfConv forward:
//   t = node_feat @ W^T [N,64]; CSR by dst; out[n,k,o]=b[o]+sum ef_s[j,k]*t[src_s[j],o]
// Round 5 (= Round 4 with compile fix): CSR build fused into ONE cooperative
// kernel (7 launches -> 2); ef permuted into dst order (ef_s) so aggregate
// reads it streaming with nontemporal loads, keeping per-XCD L2 for the t
// gather table. Nontemporal builtins need a NATIVE vector type, not
// HIP_vector_type -> use ext_vector_type(4) float.

#define FEATS 64
#define EDGE_DIM 8

typedef float nfloat4 __attribute__((ext_vector_type(4)));

// ============ Cooperative build kernel: transform + hist + scan + permute ============
__global__ void __launch_bounds__(256, 4) build_kernel(
    const float* __restrict__ nf, const float* __restrict__ W,
    const float* __restrict__ ef, const int* __restrict__ src,
    const int* __restrict__ dst,
    float* __restrict__ t, int* __restrict__ deg, int* __restrict__ offsets,
    int* __restrict__ cursor, int* __restrict__ partials, int* __restrict__ pscan,
    int* __restrict__ src_s, int* __restrict__ perm, float* __restrict__ ef_s,
    int n_nodes, int n_edges, int use_efs)
{
    cg::grid_group grid = cg::this_grid();
    __shared__ float sWt[FEATS * 65];
    __shared__ float srow[4][FEATS];
    __shared__ int sscan[256];
    __shared__ int srun;
    const int tid = threadIdx.x;
    const int nb = gridDim.x;

    // stage W^T in LDS (once per block), +1 pad
    #pragma unroll
    for (int base = 0; base < FEATS * FEATS; base += 256) {
        int idx = base + tid;
        sWt[(idx & 63) * 65 + (idx >> 6)] = W[idx];
    }
    // P0a: zero deg
    for (int i = blockIdx.x * 256 + tid; i < n_nodes; i += nb * 256) deg[i] = 0;
    __syncthreads();

    // P0b: transform, grid-stride over groups of 4 nodes
    const int r = tid >> 6, o = tid & 63;
    const int ngroups = (n_nodes + 3) >> 2;
    for (int g = blockIdx.x; g < ngroups; g += nb) {
        int node = g * 4 + r;
        if (node < n_nodes) srow[r][o] = nf[(long)node * FEATS + o];
        __syncthreads();
        if (node < n_nodes) {
            float sum = 0.f;
            #pragma unroll
            for (int i = 0; i < FEATS; i++) sum += srow[r][i] * sWt[i * 65 + o];
            t[(long)node * FEATS + o] = sum;
        }
        __syncthreads();
    }

    __threadfence();
    grid.sync();

    // P1: histogram of dst (int4, 4 edges/thread)
    const int nq = n_edges >> 2;
    for (int q = blockIdx.x * 256 + tid; q < nq; q += nb * 256) {
        int4 d4 = ((const int4*)dst)[q];
        atomicAdd(&deg[d4.x], 1); atomicAdd(&deg[d4.y], 1);
        atomicAdd(&deg[d4.z], 1); atomicAdd(&deg[d4.w], 1);
    }
    if (blockIdx.x == 0 && tid < (n_edges & 3)) atomicAdd(&deg[dst[nq * 4 + tid]], 1);

    __threadfence();
    grid.sync();

    // P2a: per-256-tile partial sums
    const int ntiles = (n_nodes + 255) >> 8;
    for (int tl = blockIdx.x; tl < ntiles; tl += nb) {
        int i = tl * 256 + tid;
        sscan[tid] = (i < n_nodes) ? deg[i] : 0;
        __syncthreads();
        for (int off = 128; off > 0; off >>= 1) {
            if (tid < off) sscan[tid] += sscan[tid + off];
            __syncthreads();
        }
        if (tid == 0) partials[tl] = sscan[0];
        __syncthreads();
    }

    __threadfence();
    grid.sync();

    // P2b: block 0 exclusive-scans partials (chunks of 256, sequential carry)
    if (blockIdx.x == 0) {
        if (tid == 0) srun = 0;
        __syncthreads();
        for (int base = 0; base < ntiles; base += 256) {
            int idx = base + tid;
            int v = (idx < ntiles) ? partials[idx] : 0;
            sscan[tid] = v;
            for (int off = 1; off < 256; off <<= 1) {
                __syncthreads();
                int x = (tid >= off) ? sscan[tid - off] : 0;
                __syncthreads();
                sscan[tid] += x;
            }
            __syncthreads();
            if (idx < ntiles) pscan[idx] = srun + sscan[tid] - v;
            __syncthreads();
            if (tid == 0) srun += sscan[255];
            __syncthreads();
        }
    }

    __threadfence();
    grid.sync();

    // P2c: per-tile local exclusive scan + addback -> offsets, cursor
    for (int tl = blockIdx.x; tl < ntiles; tl += nb) {
        int i = tl * 256 + tid;
        int v = (i < n_nodes) ? deg[i] : 0;
        sscan[tid] = v;
        for (int off = 1; off < 256; off <<= 1) {
            __syncthreads();
            int x = (tid >= off) ? sscan[tid - off] : 0;
            __syncthreads();
            sscan[tid] += x;
        }
        __syncthreads();
        if (i < n_nodes) {
            int excl = pscan[tl] + sscan[tid] - v;
            offsets[i] = excl;
            cursor[i]  = excl;
        }
        __syncthreads();
    }
    if (blockIdx.x == 0 && tid == 0) offsets[n_nodes] = n_edges;

    __threadfence();
    grid.sync();

    // P3: permute edges into dst-sorted order
    if (use_efs) {
        for (int e = blockIdx.x * 256 + tid; e < n_edges; e += nb * 256) {
            int pos = atomicAdd(&cursor[dst[e]], 1);
            src_s[pos] = src[e];
            const nfloat4* efe = (const nfloat4*)(ef + (long)e * EDGE_DIM);
            nfloat4 a = efe[0], c = efe[1];
            nfloat4* dp = (nfloat4*)(ef_s + (long)pos * EDGE_DIM);
            dp[0] = a; dp[1] = c;
        }
    } else {
        for (int e = blockIdx.x * 256 + tid; e < n_edges; e += nb * 256) {
            int pos = atomicAdd(&cursor[dst[e]], 1);
            src_s[pos] = src[e];
            perm[pos] = e;
        }
    }
}

// ============ Aggregate, streaming ef_s (nontemporal), 8-edge unroll ============
__global__ void __launch_bounds__(256) aggregate_stream_kernel(
    const float* __restrict__ t, const float* __restrict__ efs,
    const int* __restrict__ src_s, const int* __restrict__ offsets,
    const float* __restrict__ b, float* __restrict__ out, int n_nodes)
{
    int node = (blockIdx.x * 256 + threadIdx.x) >> 6;
    int o = threadIdx.x & 63;
    if (node >= n_nodes) return;

    int beg = offsets[node];
    int end = offsets[node + 1];
    float acc[EDGE_DIM];
    #pragma unroll
    for (int k = 0; k < EDGE_DIM; k++) acc[k] = 0.f;

    const nfloat4* efs4 = (const nfloat4*)efs;

    int j = beg;
    for (; j + 7 < end; j += 8) {
        int sidx[8];
        float tv[8];
        #pragma unroll
        for (int u = 0; u < 8; u++) sidx[u] = src_s[j + u];
        #pragma unroll
        for (int u = 0; u < 8; u++) tv[u] = t[(long)sidx[u] * FEATS + o];
        #pragma unroll
        for (int u = 0; u < 8; u++) {
            nfloat4 e0 = __builtin_nontemporal_load(&efs4[2l * (j + u)]);
            nfloat4 e1 = __builtin_nontemporal_load(&efs4[2l * (j + u) + 1]);
            acc[0] += e0.x * tv[u]; acc[1] += e0.y * tv[u];
            acc[2] += e0.z * tv[u]; acc[3] += e0.w * tv[u];
            acc[4] += e1.x * tv[u]; acc[5] += e1.y * tv[u];
            acc[6] += e1.z * tv[u]; acc[7] += e1.w * tv[u];
        }
    }
    for (; j < end; j++) {
        int s0 = src_s[j];
        float tv0 = t[(long)s0 * FEATS + o];
        nfloat4 e0 = __builtin_nontemporal_load(&efs4[2l * j]);
        nfloat4 e1 = __builtin_nontemporal_load(&efs4[2l * j + 1]);
        acc[0] += e0.x * tv0; acc[1] += e0.y * tv0;
        acc[2] += e0.z * tv0; acc[3] += e0.w * tv0;
        acc[4] += e1.x * tv0; acc[5] += e1.y * tv0;
        acc[6] += e1.z * tv0; acc[7] += e1.w * tv0;
    }

    float bo = b[o];
    float* op = out + (long)node * (EDGE_DIM * FEATS) + o;
    #pragma unroll
    for (int k = 0; k < EDGE_DIM; k++)
        __builtin_nontemporal_store(acc[k] + bo, op + k * FEATS);
}

// ============ Aggregate fallback: ef via perm indirection ============
__global__ void __launch_bounds__(256) aggregate_kernel(
    const float* __restrict__ t, const float* __restrict__ ef,
    const int* __restrict__ src_s, const int* __restrict__ perm,
    const int* __restrict__ offsets, const float* __restrict__ b,
    float* __restrict__ out, int n_nodes)
{
    int node = (blockIdx.x * 256 + threadIdx.x) >> 6;
    int o = threadIdx.x & 63;
    if (node >= n_nodes) return;

    int beg = offsets[node];
    int end = offsets[node + 1];
    float acc[EDGE_DIM];
    #pragma unroll
    for (int k = 0; k < EDGE_DIM; k++) acc[k] = 0.f;

    int j = beg;
    for (; j + 1 < end; j += 2) {
        int e0 = perm[j], e1 = perm[j + 1];
        int s0 = src_s[j], s1 = src_s[j + 1];
        float tv0 = t[(long)s0 * FEATS + o];
        float tv1 = t[(long)s1 * FEATS + o];
        const float4* p0 = (const float4*)(ef + (long)e0 * EDGE_DIM);
        const float4* p1 = (const float4*)(ef + (long)e1 * EDGE_DIM);
        float4 a0 = p0[0], a1 = p0[1];
        float4 c0 = p1[0], c1 = p1[1];
        acc[0] += a0.x * tv0 + c0.x * tv1;
        acc[1] += a0.y * tv0 + c0.y * tv1;
        acc[2] += a0.z * tv0 + c0.z * tv1;
        acc[3] += a0.w * tv0 + c0.w * tv1;
        acc[4] += a1.x * tv0 + c1.x * tv1;
        acc[5] += a1.y * tv0 + c1.y * tv1;
        acc[6] += a1.z * tv0 + c1.z * tv1;
        acc[7] += a1.w * tv0 + c1.w * tv1;
    }
    if (j < end) {
        int e0 = perm[j];
        int s0 = src_s[j];
        float tv0 = t[(long)s0 * FEATS + o];
        const float4* p0 = (const float4*)(ef + (long)e0 * EDGE_DIM);
        float4 a0 = p0[0], a1 = p0[1];
        acc[0] += a0.x * tv0; acc[1] += a0.y * tv0;
        acc[2] += a0.z * tv0; acc[3] += a0.w * tv0;
        acc[4] += a1.x * tv0; acc[5] += a1.y * tv0;
        acc[6] += a1.z * tv0; acc[7] += a1.w * tv0;
    }

    float bo = b[o];
    float* op = out + (long)node * (EDGE_DIM * FEATS) + o;
    #pragma unroll
    for (int k = 0; k < EDGE_DIM; k++)
        __builtin_nontemporal_store(acc[k] + bo, op + k * FEATS);
}

// ============ Non-cooperative fallback build kernels (round-3-proven) ============
__global__ void __launch_bounds__(256) transform_kernel(
    const float* __restrict__ nf, const float* __restrict__ W,
    float* __restrict__ t, int* __restrict__ deg, int n_nodes)
{
    __shared__ float sWt[FEATS * 65];
    __shared__ float srow[4][FEATS];
    const int tid = threadIdx.x;
    #pragma unroll
    for (int base = 0; base < FEATS * FEATS; base += 256) {
        int idx = base + tid;
        sWt[(idx & 63) * 65 + (idx >> 6)] = W[idx];
    }
    const int r = tid >> 6, o = tid & 63;
    const int node = blockIdx.x * 4 + r;
    if (node < n_nodes) srow[r][o] = nf[(long)node * FEATS + o];
    if (tid < 4) {
        int zn = blockIdx.x * 4 + tid;
        if (zn < n_nodes) deg[zn] = 0;
    }
    __syncthreads();
    if (node >= n_nodes) return;
    float sum = 0.f;
    #pragma unroll
    for (int i = 0; i < FEATS; i++) sum += srow[r][i] * sWt[i * 65 + o];
    t[(long)node * FEATS + o] = sum;
}

__global__ void __launch_bounds__(256) hist_kernel(
    const int* __restrict__ dst, int* __restrict__ deg, int n_edges)
{
    int i = (blockIdx.x * 256 + threadIdx.x) * 4;
    if (i + 3 < n_edges) {
        int4 d = *(const int4*)(dst + i);
        atomicAdd(&deg[d.x], 1); atomicAdd(&deg[d.y], 1);
        atomicAdd(&deg[d.z], 1); atomicAdd(&deg[d.w], 1);
    } else {
        for (int e = i; e < n_edges; e++) atomicAdd(&deg[dst[e]], 1);
    }
}

__global__ void __launch_bounds__(256) partials_kernel(
    const int* __restrict__ deg, int* __restrict__ partials, int n)
{
    __shared__ int s[256];
    int i = blockIdx.x * 256 + threadIdx.x;
    s[threadIdx.x] = (i < n) ? deg[i] : 0;
    __syncthreads();
    for (int off = 128; off > 0; off >>= 1) {
        if (threadIdx.x < off) s[threadIdx.x] += s[threadIdx.x + off];
        __syncthreads();
    }
    if (threadIdx.x == 0) partials[blockIdx.x] = s[0];
}

__global__ void __launch_bounds__(256) scan_partials_kernel(
    const int* __restrict__ partials, int* __restrict__ pscan, int nb)
{
    __shared__ int s[256];
    int tid = threadIdx.x;
    s[tid] = (tid < nb) ? partials[tid] : 0;
    for (int off = 1; off < 256; off <<= 1) {
        __syncthreads();
        int x = (tid >= off) ? s[tid - off] : 0;
        __syncthreads();
        s[tid] += x;
    }
    __syncthreads();
    pscan[tid] = (tid == 0) ? 0 : s[tid - 1];
}

__global__ void __launch_bounds__(256) scan_addback_kernel(
    const int* __restrict__ deg, const int* __restrict__ pscan,
    int* __restrict__ offsets, int* __restrict__ cursor, int n, int n_edges)
{
    __shared__ int s[256];
    int tid = threadIdx.x;
    int i = blockIdx.x * 256 + tid;
    int v = (i < n) ? deg[i] : 0;
    s[tid] = v;
    for (int off = 1; off < 256; off <<= 1) {
        __syncthreads();
        int x = (tid >= off) ? s[tid - off] : 0;
        __syncthreads();
        s[tid] += x;
    }
    __syncthreads();
    if (i < n) {
        int excl = pscan[blockIdx.x] + s[tid] - v;
        offsets[i] = excl;
        cursor[i]  = excl;
    }
    if (blockIdx.x == 0 && tid == 0) offsets[n] = n_edges;
}

__global__ void __launch_bounds__(256) permute_ef_kernel(
    const int* __restrict__ src, const int* __restrict__ dst,
    const float* __restrict__ ef, int* __restrict__ cursor,
    int* __restrict__ src_s, float* __restrict__ efs, int n_edges)
{
    int e = blockIdx.x * 256 + threadIdx.x;
    if (e >= n_edges) return;
    int pos = atomicAdd(&cursor[dst[e]], 1);
    src_s[pos] = src[e];
    const nfloat4* efe = (const nfloat4*)(ef + (long)e * EDGE_DIM);
    nfloat4 a = efe[0], c = efe[1];
    nfloat4* dp = (nfloat4*)(efs + (long)pos * EDGE_DIM);
    dp[0] = a; dp[1] = c;
}

__global__ void __launch_bounds__(256) permute_kernel(
    const int* __restrict__ src, const int* __restrict__ dst,
    int* __restrict__ cursor, int* __restrict__ src_s, int* __restrict__ perm,
    int n_edges)
{
    int e = blockIdx.x * 256 + threadIdx.x;
    if (e >= n_edges) return;
    int pos = atomicAdd(&cursor[dst[e]], 1);
    src_s[pos] = src[e];
    perm[pos] = e;
}

extern "C" void kernel_launch(void* const* d_in, const int* in_sizes, int n_in,
                              void* d_out, int out_size, void* d_ws, size_t ws_size,
                              hipStream_t stream) {
    const float* node_feat = (const float*)d_in[0];
    const float* edge_feat = (const float*)d_in[1];
    const float* W         = (const float*)d_in[2];
    const float* b         = (const float*)d_in[3];
    const int*   src       = (const int*)d_in[4];
    const int*   dst       = (const int*)d_in[5];
    float* out = (float*)d_out;

    int n_nodes = in_sizes[0] / FEATS;
    int n_edges = in_sizes[4];

    // ---- workspace carving, every array 64B-aligned ----
    char* p = (char*)d_ws;
    auto take = [&](size_t bytes) -> char* {
        char* r = p; p += (bytes + 63) & ~(size_t)63; return r;
    };
    float* t      = (float*)take((size_t)n_nodes * FEATS * 4);
    int* deg      = (int*)take((size_t)n_nodes * 4);
    int* offsets  = (int*)take(((size_t)n_nodes + 1) * 4);
    int* cursor   = (int*)take((size_t)n_nodes * 4);
    int* partials = (int*)take(4096 * 4);
    int* pscan    = (int*)take(4096 * 4);
    int* src_s    = (int*)take((size_t)n_edges * 4);
    int* perm     = (int*)take((size_t)n_edges * 4);
    float* ef_s   = (float*)take((size_t)n_edges * EDGE_DIM * 4);
    size_t used_efs = (size_t)(p - (char*)d_ws);

    int use_efs = (used_efs <= ws_size) ? 1 : 0;

    // ---- cooperative build launch (grid sized by occupancy query) ----
    int maxPerCU = 0;
    hipError_t occ_err = hipOccupancyMaxActiveBlocksPerMultiprocessor(
        &maxPerCU, build_kernel, 256, 0);
    int grid = (occ_err == hipSuccess && maxPerCU > 0) ? maxPerCU * 256 : 256;
    if (grid > 1024) grid = 1024;

    void* args[] = {
        (void*)&node_feat, (void*)&W, (void*)&edge_feat, (void*)&src, (void*)&dst,
        (void*)&t, (void*)&deg, (void*)&offsets, (void*)&cursor,
        (void*)&partials, (void*)&pscan, (void*)&src_s, (void*)&perm, (void*)&ef_s,
        (void*)&n_nodes, (void*)&n_edges, (void*)&use_efs
    };
    hipError_t lerr = hipLaunchCooperativeKernel(
        (const void*)build_kernel, dim3(grid), dim3(256), args, 0, stream);

    if (lerr != hipSuccess) {
        // deterministic non-cooperative fallback (round-3-proven path)
        const int nb_nodes = (n_nodes + 255) / 256;
        const int nb_edges = (n_edges + 255) / 256;
        transform_kernel<<<(n_nodes + 3) / 4, 256, 0, stream>>>(node_feat, W, t, deg, n_nodes);
        hist_kernel<<<(n_edges + 1023) / 1024, 256, 0, stream>>>(dst, deg, n_edges);
        partials_kernel<<<nb_nodes, 256, 0, stream>>>(deg, partials, n_nodes);
        scan_partials_kernel<<<1, 256, 0, stream>>>(partials, pscan, nb_nodes);
        scan_addback_kernel<<<nb_nodes, 256, 0, stream>>>(deg, pscan, offsets, cursor,
                                                          n_nodes, n_edges);
        if (use_efs) {
            permute_ef_kernel<<<nb_edges, 256, 0, stream>>>(
                src, dst, edge_feat, cursor, src_s, ef_s, n_edges);
        } else {
            permute_kernel<<<nb_edges, 256, 0, stream>>>(src, dst, cursor, src_s, perm, n_edges);
        }
    }

    // ---- aggregate ----
    const long total_ag = (long)n_nodes * 64;
    const int ag_blocks = (int)((total_ag + 255) / 256);
    if (use_efs) {
        aggregate_stream_kernel<<<ag_blocks, 256, 0, stream>>>(
            t, ef_s, src_s, offsets, b, out, n_nodes);
    } else {
        aggregate_kernel<<<ag_blocks, 256, 0, stream>>>(
            t, edge_feat, src_s, perm, offsets, b, out, n_nodes);
    }
}

// Round 6
// 334.420 us; speedup vs baseline: 3.3549x; 3.3549x over previous
//
#include <hip/hip_runtime.h>

// EfConv forward, CSR-based, NON-cooperative (R5 lesson: grid.sync() costs
// ~150us/sync on 8-XCD gfx950 -- never fuse phases with it).
// Chain: transform(+zero deg) -> hist -> partials -> scan -> addback ->
//        permute_ef (src_s + ef_s scattered into dst order) ->
//        aggregate_stream (streaming nontemporal ef_s, t-row gathers, 8-unroll)

#define FEATS 64
#define EDGE_DIM 8

typedef float nfloat4 __attribute__((ext_vector_type(4)));

// ---- Kernel 1: t[n][o] = sum_i nf[n][i] * W[o][i]; also zeroes deg ----
__global__ void __launch_bounds__(256) transform_kernel(
    const float* __restrict__ nf, const float* __restrict__ W,
    float* __restrict__ t, int* __restrict__ deg, int n_nodes)
{
    __shared__ float sWt[FEATS * 65];
    __shared__ float srow[4][FEATS];
    const int tid = threadIdx.x;
    #pragma unroll
    for (int base = 0; base < FEATS * FEATS; base += 256) {
        int idx = base + tid;
        sWt[(idx & 63) * 65 + (idx >> 6)] = W[idx];
    }
    const int r = tid >> 6, o = tid & 63;
    const int node = blockIdx.x * 4 + r;
    if (node < n_nodes) srow[r][o] = nf[(long)node * FEATS + o];
    if (tid < 4) {
        int zn = blockIdx.x * 4 + tid;
        if (zn < n_nodes) deg[zn] = 0;
    }
    __syncthreads();
    if (node >= n_nodes) return;
    float sum = 0.f;
    #pragma unroll
    for (int i = 0; i < FEATS; i++) sum += srow[r][i] * sWt[i * 65 + o];
    t[(long)node * FEATS + o] = sum;
}

// ---- Kernel 2: histogram of dst, 4 edges/thread ----
__global__ void __launch_bounds__(256) hist_kernel(
    const int* __restrict__ dst, int* __restrict__ deg, int n_edges)
{
    int i = (blockIdx.x * 256 + threadIdx.x) * 4;
    if (i + 3 < n_edges) {
        int4 d = *(const int4*)(dst + i);
        atomicAdd(&deg[d.x], 1); atomicAdd(&deg[d.y], 1);
        atomicAdd(&deg[d.z], 1); atomicAdd(&deg[d.w], 1);
    } else {
        for (int e = i; e < n_edges; e++) atomicAdd(&deg[dst[e]], 1);
    }
}

// ---- Kernel 3a: per-block partial sums of deg ----
__global__ void __launch_bounds__(256) partials_kernel(
    const int* __restrict__ deg, int* __restrict__ partials, int n)
{
    __shared__ int s[256];
    int i = blockIdx.x * 256 + threadIdx.x;
    s[threadIdx.x] = (i < n) ? deg[i] : 0;
    __syncthreads();
    for (int off = 128; off > 0; off >>= 1) {
        if (threadIdx.x < off) s[threadIdx.x] += s[threadIdx.x + off];
        __syncthreads();
    }
    if (threadIdx.x == 0) partials[blockIdx.x] = s[0];
}

// ---- Kernel 3b: exclusive scan of partials (single block, nb <= 256) ----
__global__ void __launch_bounds__(256) scan_partials_kernel(
    const int* __restrict__ partials, int* __restrict__ pscan, int nb)
{
    __shared__ int s[256];
    int tid = threadIdx.x;
    s[tid] = (tid < nb) ? partials[tid] : 0;
    for (int off = 1; off < 256; off <<= 1) {
        __syncthreads();
        int x = (tid >= off) ? s[tid - off] : 0;
        __syncthreads();
        s[tid] += x;
    }
    __syncthreads();
    pscan[tid] = (tid == 0) ? 0 : s[tid - 1];
}

// ---- Kernel 3c: block-local exclusive scan + addback -> offsets, cursor ----
__global__ void __launch_bounds__(256) scan_addback_kernel(
    const int* __restrict__ deg, const int* __restrict__ pscan,
    int* __restrict__ offsets, int* __restrict__ cursor, int n, int n_edges)
{
    __shared__ int s[256];
    int tid = threadIdx.x;
    int i = blockIdx.x * 256 + tid;
    int v = (i < n) ? deg[i] : 0;
    s[tid] = v;
    for (int off = 1; off < 256; off <<= 1) {
        __syncthreads();
        int x = (tid >= off) ? s[tid - off] : 0;
        __syncthreads();
        s[tid] += x;
    }
    __syncthreads();
    if (i < n) {
        int excl = pscan[blockIdx.x] + s[tid] - v;
        offsets[i] = excl;
        cursor[i]  = excl;
    }
    if (blockIdx.x == 0 && tid == 0) offsets[n] = n_edges;
}

// ---- Kernel 4: permute src and ef into dst-sorted order ----
__global__ void __launch_bounds__(256) permute_ef_kernel(
    const int* __restrict__ src, const int* __restrict__ dst,
    const float* __restrict__ ef, int* __restrict__ cursor,
    int* __restrict__ src_s, float* __restrict__ efs, int n_edges)
{
    int e = blockIdx.x * 256 + threadIdx.x;
    if (e >= n_edges) return;
    // load ef early (independent of the atomic's latency chain)
    const nfloat4* efe = (const nfloat4*)(ef + (long)e * EDGE_DIM);
    nfloat4 a = efe[0], c = efe[1];
    int s = src[e];
    int pos = atomicAdd(&cursor[dst[e]], 1);
    src_s[pos] = s;
    nfloat4* dp = (nfloat4*)(efs + (long)pos * EDGE_DIM);
    dp[0] = a; dp[1] = c;
}

// ---- Kernel 4' fallback: permute src + edge index only ----
__global__ void __launch_bounds__(256) permute_kernel(
    const int* __restrict__ src, const int* __restrict__ dst,
    int* __restrict__ cursor, int* __restrict__ src_s, int* __restrict__ perm,
    int n_edges)
{
    int e = blockIdx.x * 256 + threadIdx.x;
    if (e >= n_edges) return;
    int pos = atomicAdd(&cursor[dst[e]], 1);
    src_s[pos] = src[e];
    perm[pos] = e;
}

// ---- Kernel 5: aggregate, streaming ef_s (nontemporal), 8-edge unroll ----
__global__ void __launch_bounds__(256) aggregate_stream_kernel(
    const float* __restrict__ t, const float* __restrict__ efs,
    const int* __restrict__ src_s, const int* __restrict__ offsets,
    const float* __restrict__ b, float* __restrict__ out, int n_nodes)
{
    int node = (blockIdx.x * 256 + threadIdx.x) >> 6;
    int o = threadIdx.x & 63;
    if (node >= n_nodes) return;

    int beg = offsets[node];
    int end = offsets[node + 1];
    float acc[EDGE_DIM];
    #pragma unroll
    for (int k = 0; k < EDGE_DIM; k++) acc[k] = 0.f;

    const nfloat4* efs4 = (const nfloat4*)efs;

    int j = beg;
    for (; j + 7 < end; j += 8) {
        int sidx[8];
        float tv[8];
        #pragma unroll
        for (int u = 0; u < 8; u++) sidx[u] = src_s[j + u];
        #pragma unroll
        for (int u = 0; u < 8; u++) tv[u] = t[(long)sidx[u] * FEATS + o];
        #pragma unroll
        for (int u = 0; u < 8; u++) {
            nfloat4 e0 = __builtin_nontemporal_load(&efs4[2l * (j + u)]);
            nfloat4 e1 = __builtin_nontemporal_load(&efs4[2l * (j + u) + 1]);
            acc[0] += e0.x * tv[u]; acc[1] += e0.y * tv[u];
            acc[2] += e0.z * tv[u]; acc[3] += e0.w * tv[u];
            acc[4] += e1.x * tv[u]; acc[5] += e1.y * tv[u];
            acc[6] += e1.z * tv[u]; acc[7] += e1.w * tv[u];
        }
    }
    for (; j < end; j++) {
        int s0 = src_s[j];
        float tv0 = t[(long)s0 * FEATS + o];
        nfloat4 e0 = __builtin_nontemporal_load(&efs4[2l * j]);
        nfloat4 e1 = __builtin_nontemporal_load(&efs4[2l * j + 1]);
        acc[0] += e0.x * tv0; acc[1] += e0.y * tv0;
        acc[2] += e0.z * tv0; acc[3] += e0.w * tv0;
        acc[4] += e1.x * tv0; acc[5] += e1.y * tv0;
        acc[6] += e1.z * tv0; acc[7] += e1.w * tv0;
    }

    float bo = b[o];
    float* op = out + (long)node * (EDGE_DIM * FEATS) + o;
    #pragma unroll
    for (int k = 0; k < EDGE_DIM; k++)
        __builtin_nontemporal_store(acc[k] + bo, op + k * FEATS);
}

// ---- Kernel 5' fallback: aggregate, ef via perm indirection ----
__global__ void __launch_bounds__(256) aggregate_kernel(
    const float* __restrict__ t, const float* __restrict__ ef,
    const int* __restrict__ src_s, const int* __restrict__ perm,
    const int* __restrict__ offsets, const float* __restrict__ b,
    float* __restrict__ out, int n_nodes)
{
    int node = (blockIdx.x * 256 + threadIdx.x) >> 6;
    int o = threadIdx.x & 63;
    if (node >= n_nodes) return;

    int beg = offsets[node];
    int end = offsets[node + 1];
    float acc[EDGE_DIM];
    #pragma unroll
    for (int k = 0; k < EDGE_DIM; k++) acc[k] = 0.f;

    int j = beg;
    for (; j + 1 < end; j += 2) {
        int e0 = perm[j], e1 = perm[j + 1];
        int s0 = src_s[j], s1 = src_s[j + 1];
        float tv0 = t[(long)s0 * FEATS + o];
        float tv1 = t[(long)s1 * FEATS + o];
        const float4* p0 = (const float4*)(ef + (long)e0 * EDGE_DIM);
        const float4* p1 = (const float4*)(ef + (long)e1 * EDGE_DIM);
        float4 a0 = p0[0], a1 = p0[1];
        float4 c0 = p1[0], c1 = p1[1];
        acc[0] += a0.x * tv0 + c0.x * tv1;
        acc[1] += a0.y * tv0 + c0.y * tv1;
        acc[2] += a0.z * tv0 + c0.z * tv1;
        acc[3] += a0.w * tv0 + c0.w * tv1;
        acc[4] += a1.x * tv0 + c1.x * tv1;
        acc[5] += a1.y * tv0 + c1.y * tv1;
        acc[6] += a1.z * tv0 + c1.z * tv1;
        acc[7] += a1.w * tv0 + c1.w * tv1;
    }
    if (j < end) {
        int e0 = perm[j];
        int s0 = src_s[j];
        float tv0 = t[(long)s0 * FEATS + o];
        const float4* p0 = (const float4*)(ef + (long)e0 * EDGE_DIM);
        float4 a0 = p0[0], a1 = p0[1];
        acc[0] += a0.x * tv0; acc[1] += a0.y * tv0;
        acc[2] += a0.z * tv0; acc[3] += a0.w * tv0;
        acc[4] += a1.x * tv0; acc[5] += a1.y * tv0;
        acc[6] += a1.z * tv0; acc[7] += a1.w * tv0;
    }

    float bo = b[o];
    float* op = out + (long)node * (EDGE_DIM * FEATS) + o;
    #pragma unroll
    for (int k = 0; k < EDGE_DIM; k++)
        __builtin_nontemporal_store(acc[k] + bo, op + k * FEATS);
}

extern "C" void kernel_launch(void* const* d_in, const int* in_sizes, int n_in,
                              void* d_out, int out_size, void* d_ws, size_t ws_size,
                              hipStream_t stream) {
    const float* node_feat = (const float*)d_in[0];
    const float* edge_feat = (const float*)d_in[1];
    const float* W         = (const float*)d_in[2];
    const float* b         = (const float*)d_in[3];
    const int*   src       = (const int*)d_in[4];
    const int*   dst       = (const int*)d_in[5];
    float* out = (float*)d_out;

    int n_nodes = in_sizes[0] / FEATS;
    int n_edges = in_sizes[4];

    // ---- workspace carving, every array 64B-aligned ----
    char* p = (char*)d_ws;
    auto take = [&](size_t bytes) -> char* {
        char* r = p; p += (bytes + 63) & ~(size_t)63; return r;
    };
    float* t      = (float*)take((size_t)n_nodes * FEATS * 4);
    int* deg      = (int*)take((size_t)n_nodes * 4);
    int* offsets  = (int*)take(((size_t)n_nodes + 1) * 4);
    int* cursor   = (int*)take((size_t)n_nodes * 4);
    int* partials = (int*)take(4096 * 4);
    int* pscan    = (int*)take(4096 * 4);
    int* src_s    = (int*)take((size_t)n_edges * 4);
    int* perm     = (int*)take((size_t)n_edges * 4);
    float* ef_s   = (float*)take((size_t)n_edges * EDGE_DIM * 4);
    size_t used_efs = (size_t)(p - (char*)d_ws);

    const int use_efs = (used_efs <= ws_size) ? 1 : 0;

    const int nb_nodes = (n_nodes + 255) / 256;
    const int nb_edges = (n_edges + 255) / 256;

    transform_kernel<<<(n_nodes + 3) / 4, 256, 0, stream>>>(node_feat, W, t, deg, n_nodes);
    hist_kernel<<<(n_edges + 1023) / 1024, 256, 0, stream>>>(dst, deg, n_edges);
    partials_kernel<<<nb_nodes, 256, 0, stream>>>(deg, partials, n_nodes);
    scan_partials_kernel<<<1, 256, 0, stream>>>(partials, pscan, nb_nodes);
    scan_addback_kernel<<<nb_nodes, 256, 0, stream>>>(deg, pscan, offsets, cursor,
                                                      n_nodes, n_edges);

    const long total_ag = (long)n_nodes * 64;
    const int ag_blocks = (int)((total_ag + 255) / 256);
    if (use_efs) {
        permute_ef_kernel<<<nb_edges, 256, 0, stream>>>(
            src, dst, edge_feat, cursor, src_s, ef_s, n_edges);
        aggregate_stream_kernel<<<ag_blocks, 256, 0, stream>>>(
            t, ef_s, src_s, offsets, b, out, n_nodes);
    } else {
        permute_kernel<<<nb_edges, 256, 0, stream>>>(src, dst, cursor, src_s, perm, n_edges);
        aggregate_kernel<<<ag_blocks, 256, 0, stream>>>(
            t, edge_feat, src_s, perm, offsets, b, out, n_nodes);
    }
}